// Round 11
// baseline (293.394 us; speedup 1.0000x reference)
//
#include <hip/hip_runtime.h>
#include <math.h>
#include <float.h>

#define B_ 1024
#define R_ 12
#define N_ 2048

typedef float floatx4 __attribute__((ext_vector_type(4)));

// ---------------------------------------------------------------------------
// const_kernel (1 block, 1024 thr):
//   M[i,j] = Wq2[i,:] . Wk2[j,:]   (32x32)
//   v[j]   = Wk2[j,:] . bq2        u[i] = Wq2[i,:] . bk2       k0 = bq2 . bk2
//   WkT[j][0..10] = Wk1[t][j],  WkT[j][11] = bk1[j]   (32x12, row-contiguous)
// ---------------------------------------------------------------------------
__global__ void __launch_bounds__(1024) const_kernel(
    const float* __restrict__ Wq2, const float* __restrict__ bq2,
    const float* __restrict__ Wk2, const float* __restrict__ bk2,
    const float* __restrict__ Wk1, const float* __restrict__ bk1,
    float* __restrict__ Mmat, float* __restrict__ uvec,
    float* __restrict__ vvec, float* __restrict__ k0p,
    float* __restrict__ WkT)
{
    const int t = threadIdx.x;
    const int i = t >> 5, j = t & 31;
    float m = 0.0f;
    for (int d = 0; d < 64; d++) m += Wq2[i * 64 + d] * Wk2[j * 64 + d];
    Mmat[t] = m;
    if (t < 32) {
        float v = 0.0f;
        for (int d = 0; d < 64; d++) v += Wk2[t * 64 + d] * bq2[d];
        vvec[t] = v;
    } else if (t < 64) {
        float u = 0.0f;
        for (int d = 0; d < 64; d++) u += Wq2[(t - 32) * 64 + d] * bk2[d];
        uvec[t - 32] = u;
    } else if (t == 64) {
        float k = 0.0f;
        for (int d = 0; d < 64; d++) k += bq2[d] * bk2[d];
        k0p[0] = k;
    }
    if (t < 384) {
        const int jj = t / 12, e = t - jj * 12;
        WkT[t] = (e < 11) ? Wk1[e * 32 + jj] : bk1[jj];
    }
}

// ---------------------------------------------------------------------------
// prep_kernel: ONE thread per (b,r).  Q held as named floatx4 Q0..Q7.
// Writes TRANSPOSED qpT[b][j][r].  Packs mask bits.
// ---------------------------------------------------------------------------
__global__ void __launch_bounds__(256) prep_kernel(
    const float* __restrict__ rss,                       // [B*R]
    const float* __restrict__ Wg1, const float* __restrict__ bg1,
    const float* __restrict__ Wg2, const float* __restrict__ bg2,
    const float* __restrict__ Wq1, const float* __restrict__ bq1,
    const float* __restrict__ Mmat, const float* __restrict__ uvec,
    const float* __restrict__ vvec, const float* __restrict__ k0p,
    const int*   __restrict__ mask,                      // [R,N]
    float* __restrict__ qpT,                             // [B][32][12]
    float* __restrict__ cc,                              // [B*R]
    int*   __restrict__ maskbits,                        // [N]
    float* __restrict__ inten_out)                       // [B*R]
{
    const int gt = blockIdx.x * 256 + threadIdx.x;

    if (gt < N_) {
        int bits = 0;
#pragma unroll
        for (int r = 0; r < R_; r++) bits |= (mask[r * N_ + gt] != 0) << r;
        maskbits[gt] = bits;
    }

    if (gt >= B_ * R_) return;
    const int b = gt / 12, r = gt - b * 12;

    const float x = rss[gt];
    const float hard = (x > 0.5f) ? 1.0f : 0.0f;

    float s2 = bg2[0];
#pragma unroll
    for (int i = 0; i < 16; i++)
        s2 += fmaxf(x * Wg1[i] + bg1[i], 0.0f) * Wg2[i];
    const float gate = 1.0f / (1.0f + __expf(-s2));
    const float iw = hard * gate;
    const float xm = x * iw;

    const floatx4* vv = reinterpret_cast<const floatx4*>(vvec);
    floatx4 Q0 = vv[0], Q1 = vv[1], Q2 = vv[2], Q3 = vv[3];
    floatx4 Q4 = vv[4], Q5 = vv[5], Q6 = vv[6], Q7 = vv[7];
    float c = k0p[0];

#pragma unroll
    for (int i = 0; i < 32; i++) {
        const float h = fmaxf(xm * Wq1[i] + bq1[i], 0.0f);
        const floatx4* mr = reinterpret_cast<const floatx4*>(Mmat + i * 32);
        Q0 += h * mr[0]; Q1 += h * mr[1]; Q2 += h * mr[2]; Q3 += h * mr[3];
        Q4 += h * mr[4]; Q5 += h * mr[5]; Q6 += h * mr[6]; Q7 += h * mr[7];
        c  += h * uvec[i];
    }

    float* qb = qpT + (size_t)b * 384 + r;
#define STQ(k)                          \
    qb[(4 * k + 0) * 12] = Q##k .x;     \
    qb[(4 * k + 1) * 12] = Q##k .y;     \
    qb[(4 * k + 2) * 12] = Q##k .z;     \
    qb[(4 * k + 3) * 12] = Q##k .w;
    STQ(0) STQ(1) STQ(2) STQ(3) STQ(4) STQ(5) STQ(6) STQ(7)
#undef STQ

    cc[gt] = c;
    inten_out[gt] = iw;
}

// ---------------------------------------------------------------------------
// main_kernel: grid 512, 256 thr x 8 LEDs, TWO batches per block (b, b+512)
// software-pipelined: batch1 loads issue before batch0 softmax/store, so
// VMEM flight and store drain overlap VALU.  All state named vectors.
// NOTE: pasted numeric tokens need a space before member access (F##0 .x),
// else "0.x" lexes as one pp-number and ## forms an invalid token.
// ---------------------------------------------------------------------------
#define FOR_R(OP) OP(0) OP(1) OP(2) OP(3) OP(4) OP(5) OP(6) OP(7) OP(8) OP(9) OP(10) OP(11)
#define FOR_R2(OP, X) OP(0,X) OP(1,X) OP(2,X) OP(3,X) OP(4,X) OP(5,X) OP(6,X) OP(7,X) OP(8,X) OP(9,X) OP(10,X) OP(11,X)

// transpose 8 LEDs + near-field bias for one batch; O = output prefix
#define TRANS_BIAS(O, F, P, PX, PY, PZ)                                 \
    const floatx4 O##A0 = {F##0 .x, F##2 .x, F##4 .x, F##6 .x};         \
    const floatx4 O##A1 = {F##0 .y, F##2 .y, F##4 .y, F##6 .y};         \
    const floatx4 O##A2 = {F##0 .z, F##2 .z, F##4 .z, F##6 .z};         \
    const floatx4 O##A3 = {F##0 .w, F##2 .w, F##4 .w, F##6 .w};         \
    const floatx4 O##A4 = {F##1 .x, F##3 .x, F##5 .x, F##7 .x};         \
    const floatx4 O##A5 = {F##1 .y, F##3 .y, F##5 .y, F##7 .y};         \
    const floatx4 O##A6 = {F##1 .z, F##3 .z, F##5 .z, F##7 .z};         \
    const floatx4 O##A7 = {F##1 .w, F##3 .w, F##5 .w, F##7 .w};         \
    const floatx4 O##A8 = {P##0 .x, P##0 .w, P##1 .z, P##2 .y};         \
    const floatx4 O##A9 = {P##0 .y, P##1 .x, P##1 .w, P##2 .z};         \
    const floatx4 O##A10 = {P##0 .z, P##1 .y, P##2 .x, P##2 .w};        \
    const floatx4 O##B0 = {F##8 .x, F##10 .x, F##12 .x, F##14 .x};      \
    const floatx4 O##B1 = {F##8 .y, F##10 .y, F##12 .y, F##14 .y};      \
    const floatx4 O##B2 = {F##8 .z, F##10 .z, F##12 .z, F##14 .z};      \
    const floatx4 O##B3 = {F##8 .w, F##10 .w, F##12 .w, F##14 .w};      \
    const floatx4 O##B4 = {F##9 .x, F##11 .x, F##13 .x, F##15 .x};      \
    const floatx4 O##B5 = {F##9 .y, F##11 .y, F##13 .y, F##15 .y};      \
    const floatx4 O##B6 = {F##9 .z, F##11 .z, F##13 .z, F##15 .z};      \
    const floatx4 O##B7 = {F##9 .w, F##11 .w, F##13 .w, F##15 .w};      \
    const floatx4 O##B8 = {P##3 .x, P##3 .w, P##4 .z, P##5 .y};         \
    const floatx4 O##B9 = {P##3 .y, P##4 .x, P##4 .w, P##5 .z};         \
    const floatx4 O##B10 = {P##3 .z, P##4 .y, P##5 .x, P##5 .w};        \
    const floatx4 O##DXA = PX - O##A8, O##DYA = PY - O##A9, O##DZA = PZ - O##A10; \
    const floatx4 O##BIA = nfc * (O##DXA * O##DXA + O##DYA * O##DYA + O##DZA * O##DZA); \
    const floatx4 O##DXB = PX - O##B8, O##DYB = PY - O##B9, O##DZB = PZ - O##B10; \
    const floatx4 O##BIB = nfc * (O##DXB * O##DXB + O##DYB * O##DYB + O##DZB * O##DZB);

// fused K-MLP + projected-query dots for 8 LEDs (halves PA/PB) from SQ
#define JLOOP(PA, PB, SQ)                                               \
    _Pragma("unroll 2")                                                 \
    for (int j = 0; j < 32; j++) {                                      \
        const floatx4 w0 = *reinterpret_cast<const floatx4*>(&sW[j * 12]); \
        const floatx4 w1 = *reinterpret_cast<const floatx4*>(&sW[j * 12 + 4]); \
        const floatx4 w2 = *reinterpret_cast<const floatx4*>(&sW[j * 12 + 8]); \
        const floatx4 q0 = *reinterpret_cast<const floatx4*>(&SQ[j * 12]); \
        const floatx4 q1 = *reinterpret_cast<const floatx4*>(&SQ[j * 12 + 4]); \
        const floatx4 q2 = *reinterpret_cast<const floatx4*>(&SQ[j * 12 + 8]); \
        floatx4 HA = {w2.w, w2.w, w2.w, w2.w};                          \
        floatx4 HB = HA;                                                \
        HA += PA##0 * w0.x;  HB += PB##0 * w0.x;                        \
        HA += PA##1 * w0.y;  HB += PB##1 * w0.y;                        \
        HA += PA##2 * w0.z;  HB += PB##2 * w0.z;                        \
        HA += PA##3 * w0.w;  HB += PB##3 * w0.w;                        \
        HA += PA##4 * w1.x;  HB += PB##4 * w1.x;                        \
        HA += PA##5 * w1.y;  HB += PB##5 * w1.y;                        \
        HA += PA##6 * w1.z;  HB += PB##6 * w1.z;                        \
        HA += PA##7 * w1.w;  HB += PB##7 * w1.w;                        \
        HA += PA##8 * w2.x;  HB += PB##8 * w2.x;                        \
        HA += PA##9 * w2.y;  HB += PB##9 * w2.y;                        \
        HA += PA##10 * w2.z; HB += PB##10 * w2.z;                       \
        HA.x = fmaxf(HA.x, 0.0f); HA.y = fmaxf(HA.y, 0.0f);             \
        HA.z = fmaxf(HA.z, 0.0f); HA.w = fmaxf(HA.w, 0.0f);             \
        HB.x = fmaxf(HB.x, 0.0f); HB.y = fmaxf(HB.y, 0.0f);             \
        HB.z = fmaxf(HB.z, 0.0f); HB.w = fmaxf(HB.w, 0.0f);             \
        AA0 += HA * q0.x;  AB0 += HB * q0.x;                            \
        AA1 += HA * q0.y;  AB1 += HB * q0.y;                            \
        AA2 += HA * q0.z;  AB2 += HB * q0.z;                            \
        AA3 += HA * q0.w;  AB3 += HB * q0.w;                            \
        AA4 += HA * q1.x;  AB4 += HB * q1.x;                            \
        AA5 += HA * q1.y;  AB5 += HB * q1.y;                            \
        AA6 += HA * q1.z;  AB6 += HB * q1.z;                            \
        AA7 += HA * q1.w;  AB7 += HB * q1.w;                            \
        AA8 += HA * q2.x;  AB8 += HB * q2.x;                            \
        AA9 += HA * q2.y;  AB9 += HB * q2.y;                            \
        AA10 += HA * q2.z; AB10 += HB * q2.z;                           \
        AA11 += HA * q2.w; AB11 += HB * q2.w;                           \
    }

#define MASK_R(r)                                            \
    AA##r .x = ((mbA.x >> r) & 1) ? AA##r .x : -FLT_MAX;     \
    AA##r .y = ((mbA.y >> r) & 1) ? AA##r .y : -FLT_MAX;     \
    AA##r .z = ((mbA.z >> r) & 1) ? AA##r .z : -FLT_MAX;     \
    AA##r .w = ((mbA.w >> r) & 1) ? AA##r .w : -FLT_MAX;     \
    AB##r .x = ((mbB.x >> r) & 1) ? AB##r .x : -FLT_MAX;     \
    AB##r .y = ((mbB.y >> r) & 1) ? AB##r .y : -FLT_MAX;     \
    AB##r .z = ((mbB.z >> r) & 1) ? AB##r .z : -FLT_MAX;     \
    AB##r .w = ((mbB.w >> r) & 1) ? AB##r .w : -FLT_MAX;

#define WMAX2_R(r, RM) {                                                \
    float v = fmaxf(fmaxf(fmaxf(AA##r .x, AA##r .y), fmaxf(AA##r .z, AA##r .w)), \
                    fmaxf(fmaxf(AB##r .x, AB##r .y), fmaxf(AB##r .z, AB##r .w))); \
    _Pragma("unroll")                                                   \
    for (int off = 32; off >= 1; off >>= 1) v = fmaxf(v, __shfl_xor(v, off)); \
    if (lane == 0) RM[wave * 12 + r] = v; }

#define FMAX2_R(r, RM) float M##r = RM[r];                              \
    { _Pragma("unroll")                                                 \
      for (int w = 1; w < 4; w++) M##r = fmaxf(M##r, RM[w * 12 + r]); }

#define EXP2_R(r, RS) {                                                 \
    AA##r .x = __expf(AA##r .x - M##r); AA##r .y = __expf(AA##r .y - M##r); \
    AA##r .z = __expf(AA##r .z - M##r); AA##r .w = __expf(AA##r .w - M##r); \
    AB##r .x = __expf(AB##r .x - M##r); AB##r .y = __expf(AB##r .y - M##r); \
    AB##r .z = __expf(AB##r .z - M##r); AB##r .w = __expf(AB##r .w - M##r); \
    float v = ((AA##r .x + AA##r .y) + (AA##r .z + AA##r .w))           \
            + ((AB##r .x + AB##r .y) + (AB##r .z + AB##r .w));          \
    _Pragma("unroll")                                                   \
    for (int off = 32; off >= 1; off >>= 1) v += __shfl_xor(v, off);    \
    if (lane == 0) RS[wave * 12 + r] = v; }

#define FSUM2_R(r, RS) float S##r = RS[r];                              \
    { _Pragma("unroll")                                                 \
      for (int w = 1; w < 4; w++) S##r += RS[w * 12 + r]; }             \
    S##r = 1.0f / S##r;

#define STORE2_R(r, OUTP) {                                             \
    floatx4 vA = AA##r * S##r;                                          \
    floatx4 vB = AB##r * S##r;                                          \
    __builtin_nontemporal_store(vA, reinterpret_cast<floatx4*>(OUTP + (size_t)r * N_)); \
    __builtin_nontemporal_store(vB, reinterpret_cast<floatx4*>(OUTP + (size_t)r * N_ + 4)); }

__global__ void __launch_bounds__(256, 1) main_kernel(
    const float* __restrict__ ledf,     // [B,N,8]
    const float* __restrict__ ledp,     // [B,N,3]
    const float* __restrict__ prevp,    // [B,3]
    const int*   __restrict__ maskbits, // [N]
    const float* __restrict__ WkT,      // [32][12]
    const float* __restrict__ qpT,      // [B][32][12]
    const float* __restrict__ cc,       // [B*R]
    const float* __restrict__ sigp,     // [1]
    float* __restrict__ out)            // [B,R,N]
{
    const int bid = blockIdx.x;          // 0..511
    const int b0 = bid, b1 = bid + 512;
    const int tid = threadIdx.x;
    const int lane = tid & 63;
    const int wave = tid >> 6;           // 0..3
    const int n0 = tid * 8;

    __shared__ float sW[384], sQ0[384], sQ1[384];
    __shared__ float redM0[48], redS0[48], redM1[48], redS1[48];

    for (int i = tid; i < 384; i += 256) {
        sW[i] = WkT[i];
        sQ0[i] = qpT[(size_t)b0 * 384 + i];
        sQ1[i] = qpT[(size_t)b1 * 384 + i];
    }

    const float sig = sigp[0];
    const float nfc = -0.5f / (sig * sig);
    const float p0a = prevp[b0 * 3 + 0], p1a = prevp[b0 * 3 + 1], p2a = prevp[b0 * 3 + 2];
    const float p0b = prevp[b1 * 3 + 0], p1b = prevp[b1 * 3 + 1], p2b = prevp[b1 * 3 + 2];
    const float* __restrict__ ccb0 = cc + b0 * 12;
    const float* __restrict__ ccb1 = cc + b1 * 12;

    // ---- batch0 raw loads
    const floatx4* pf  = reinterpret_cast<const floatx4*>(ledf + ((size_t)b0 * N_ + n0) * 8);
    const floatx4* pp4 = reinterpret_cast<const floatx4*>(ledp + ((size_t)b0 * N_ + n0) * 3);
    const int4*    pm  = reinterpret_cast<const int4*>(maskbits + n0);
    const floatx4 F0 = pf[0],  F1 = pf[1],  F2 = pf[2],  F3 = pf[3];
    const floatx4 F4 = pf[4],  F5 = pf[5],  F6 = pf[6],  F7 = pf[7];
    const floatx4 F8 = pf[8],  F9 = pf[9],  F10 = pf[10], F11 = pf[11];
    const floatx4 F12 = pf[12], F13 = pf[13], F14 = pf[14], F15 = pf[15];
    const floatx4 pa0 = pp4[0], pa1 = pp4[1], pa2 = pp4[2];
    const floatx4 pa3 = pp4[3], pa4 = pp4[4], pa5 = pp4[5];
    const int4 mbA = pm[0], mbB = pm[1];     // mask is batch-independent

    TRANS_BIAS(X, F, pa, p0a, p1a, p2a)

#define INIT_R(r) floatx4 AA##r = XBIA + ccb0[r]; floatx4 AB##r = XBIB + ccb0[r];
    FOR_R(INIT_R)

    __syncthreads();   // staging visible

    JLOOP(XA, XB, sQ0)
    FOR_R(MASK_R)

    // ---- issue batch1 loads: in flight during batch0 softmax+store
    const floatx4* gf  = reinterpret_cast<const floatx4*>(ledf + ((size_t)b1 * N_ + n0) * 8);
    const floatx4* gp4 = reinterpret_cast<const floatx4*>(ledp + ((size_t)b1 * N_ + n0) * 3);
    const floatx4 G0 = gf[0],  G1 = gf[1],  G2 = gf[2],  G3 = gf[3];
    const floatx4 G4 = gf[4],  G5 = gf[5],  G6 = gf[6],  G7 = gf[7];
    const floatx4 G8 = gf[8],  G9 = gf[9],  G10 = gf[10], G11 = gf[11];
    const floatx4 G12 = gf[12], G13 = gf[13], G14 = gf[14], G15 = gf[15];
    const floatx4 ga0 = gp4[0], ga1 = gp4[1], ga2 = gp4[2];
    const floatx4 ga3 = gp4[3], ga4 = gp4[4], ga5 = gp4[5];

    // ---- batch0 softmax + store
    {
        FOR_R2(WMAX2_R, redM0)
        __syncthreads();
        FOR_R2(FMAX2_R, redM0)
        FOR_R2(EXP2_R, redS0)
        __syncthreads();
        FOR_R2(FSUM2_R, redS0)
        float* outp = out + (size_t)b0 * R_ * N_ + n0;
        FOR_R2(STORE2_R, outp)
    }

    // ---- batch1 compute (store drain of batch0 overlaps this)
    TRANS_BIAS(Y, G, ga, p0b, p1b, p2b)

#define REINIT_R(r) AA##r = YBIA + ccb1[r]; AB##r = YBIB + ccb1[r];
    FOR_R(REINIT_R)

    JLOOP(YA, YB, sQ1)
    FOR_R(MASK_R)

    {
        FOR_R2(WMAX2_R, redM1)
        __syncthreads();
        FOR_R2(FMAX2_R, redM1)
        FOR_R2(EXP2_R, redS1)
        __syncthreads();
        FOR_R2(FSUM2_R, redS1)
        float* outp = out + (size_t)b1 * R_ * N_ + n0;
        FOR_R2(STORE2_R, outp)
    }
}

// ---------------------------------------------------------------------------
extern "C" void kernel_launch(void* const* d_in, const int* in_sizes, int n_in,
                              void* d_out, int out_size, void* d_ws, size_t ws_size,
                              hipStream_t stream) {
    const float* rss  = (const float*)d_in[0];
    const float* ledf = (const float*)d_in[1];
    const float* ledp = (const float*)d_in[2];
    const float* prevp= (const float*)d_in[3];
    const int*   mask = (const int*)  d_in[4];
    const float* Wg1  = (const float*)d_in[5];
    const float* bg1  = (const float*)d_in[6];
    const float* Wg2  = (const float*)d_in[7];
    const float* bg2  = (const float*)d_in[8];
    const float* Wq1  = (const float*)d_in[9];
    const float* bq1  = (const float*)d_in[10];
    const float* Wq2  = (const float*)d_in[11];
    const float* bq2  = (const float*)d_in[12];
    const float* Wk1  = (const float*)d_in[13];
    const float* bk1  = (const float*)d_in[14];
    const float* Wk2  = (const float*)d_in[15];
    const float* bk2  = (const float*)d_in[16];
    const float* sigp = (const float*)d_in[17];

    float* out = (float*)d_out;
    float* inten = out + (size_t)B_ * R_ * N_;     // intensity_weight [B,R] tail

    float* qpT      = (float*)d_ws;                // [B][32][12]
    float* cc       = qpT + (size_t)B_ * 384;      // [B*R]
    int*   maskbits = (int*)(cc + B_ * R_);        // [N]
    float* Mmat     = (float*)(maskbits + N_);     // [32,32]
    float* uvec     = Mmat + 1024;                 // [32]
    float* vvec     = uvec + 32;                   // [32]
    float* k0p      = vvec + 32;                   // [1]
    float* WkT      = k0p + 4;                     // [32*12] (16B aligned)

    const_kernel<<<1, 1024, 0, stream>>>(Wq2, bq2, Wk2, bk2, Wk1, bk1,
                                         Mmat, uvec, vvec, k0p, WkT);

    prep_kernel<<<(B_ * R_ + 255) / 256, 256, 0, stream>>>(
        rss, Wg1, bg1, Wg2, bg2, Wq1, bq1,
        Mmat, uvec, vvec, k0p, mask, qpT, cc, maskbits, inten);

    main_kernel<<<512, 256, 0, stream>>>(
        ledf, ledp, prevp, maskbits, WkT, qpT, cc, sigp, out);
}

// Round 12
// 268.682 us; speedup vs baseline: 1.0920x; 1.0920x over previous
//
#include <hip/hip_runtime.h>
#include <math.h>
#include <float.h>

#define B_ 1024
#define R_ 12
#define N_ 2048

typedef float floatx4 __attribute__((ext_vector_type(4)));

// ---------------------------------------------------------------------------
// const_kernel (1 block, 1024 thr):
//   M[i,j] = Wq2[i,:] . Wk2[j,:]   (32x32)
//   v[j]   = Wk2[j,:] . bq2        u[i] = Wq2[i,:] . bk2       k0 = bq2 . bk2
//   WkT[j][0..10] = Wk1[t][j],  WkT[j][11] = bk1[j]   (32x12, row-contiguous)
// ---------------------------------------------------------------------------
__global__ void __launch_bounds__(1024) const_kernel(
    const float* __restrict__ Wq2, const float* __restrict__ bq2,
    const float* __restrict__ Wk2, const float* __restrict__ bk2,
    const float* __restrict__ Wk1, const float* __restrict__ bk1,
    float* __restrict__ Mmat, float* __restrict__ uvec,
    float* __restrict__ vvec, float* __restrict__ k0p,
    float* __restrict__ WkT)
{
    const int t = threadIdx.x;
    const int i = t >> 5, j = t & 31;
    float m = 0.0f;
    for (int d = 0; d < 64; d++) m += Wq2[i * 64 + d] * Wk2[j * 64 + d];
    Mmat[t] = m;
    if (t < 32) {
        float v = 0.0f;
        for (int d = 0; d < 64; d++) v += Wk2[t * 64 + d] * bq2[d];
        vvec[t] = v;
    } else if (t < 64) {
        float u = 0.0f;
        for (int d = 0; d < 64; d++) u += Wq2[(t - 32) * 64 + d] * bk2[d];
        uvec[t - 32] = u;
    } else if (t == 64) {
        float k = 0.0f;
        for (int d = 0; d < 64; d++) k += bq2[d] * bk2[d];
        k0p[0] = k;
    }
    if (t < 384) {
        const int jj = t / 12, e = t - jj * 12;
        WkT[t] = (e < 11) ? Wk1[e * 32 + jj] : bk1[jj];
    }
}

// ---------------------------------------------------------------------------
// prep_kernel: ONE thread per (b,r).  Q held as named floatx4 Q0..Q7.
// Writes TRANSPOSED qpT[b][j][r].  Packs mask bits.
// ---------------------------------------------------------------------------
__global__ void __launch_bounds__(256) prep_kernel(
    const float* __restrict__ rss,                       // [B*R]
    const float* __restrict__ Wg1, const float* __restrict__ bg1,
    const float* __restrict__ Wg2, const float* __restrict__ bg2,
    const float* __restrict__ Wq1, const float* __restrict__ bq1,
    const float* __restrict__ Mmat, const float* __restrict__ uvec,
    const float* __restrict__ vvec, const float* __restrict__ k0p,
    const int*   __restrict__ mask,                      // [R,N]
    float* __restrict__ qpT,                             // [B][32][12]
    float* __restrict__ cc,                              // [B*R]
    int*   __restrict__ maskbits,                        // [N]
    float* __restrict__ inten_out)                       // [B*R]
{
    const int gt = blockIdx.x * 256 + threadIdx.x;

    if (gt < N_) {
        int bits = 0;
#pragma unroll
        for (int r = 0; r < R_; r++) bits |= (mask[r * N_ + gt] != 0) << r;
        maskbits[gt] = bits;
    }

    if (gt >= B_ * R_) return;
    const int b = gt / 12, r = gt - b * 12;

    const float x = rss[gt];
    const float hard = (x > 0.5f) ? 1.0f : 0.0f;

    float s2 = bg2[0];
#pragma unroll
    for (int i = 0; i < 16; i++)
        s2 += fmaxf(x * Wg1[i] + bg1[i], 0.0f) * Wg2[i];
    const float gate = 1.0f / (1.0f + __expf(-s2));
    const float iw = hard * gate;
    const float xm = x * iw;

    const floatx4* vv = reinterpret_cast<const floatx4*>(vvec);
    floatx4 Q0 = vv[0], Q1 = vv[1], Q2 = vv[2], Q3 = vv[3];
    floatx4 Q4 = vv[4], Q5 = vv[5], Q6 = vv[6], Q7 = vv[7];
    float c = k0p[0];

#pragma unroll
    for (int i = 0; i < 32; i++) {
        const float h = fmaxf(xm * Wq1[i] + bq1[i], 0.0f);
        const floatx4* mr = reinterpret_cast<const floatx4*>(Mmat + i * 32);
        Q0 += h * mr[0]; Q1 += h * mr[1]; Q2 += h * mr[2]; Q3 += h * mr[3];
        Q4 += h * mr[4]; Q5 += h * mr[5]; Q6 += h * mr[6]; Q7 += h * mr[7];
        c  += h * uvec[i];
    }

    float* qb = qpT + (size_t)b * 384 + r;
#define STQ(k)                          \
    qb[(4 * k + 0) * 12] = Q##k .x;     \
    qb[(4 * k + 1) * 12] = Q##k .y;     \
    qb[(4 * k + 2) * 12] = Q##k .z;     \
    qb[(4 * k + 3) * 12] = Q##k .w;
    STQ(0) STQ(1) STQ(2) STQ(3) STQ(4) STQ(5) STQ(6) STQ(7)
#undef STQ

    cc[gt] = c;
    inten_out[gt] = iw;
}

// ---------------------------------------------------------------------------
// main_kernel: grid 512, 256 thr x 8 LEDs, TWO batches per block (b, b+512).
// Batch1 loads are issued after batch0's j-loop and PINNED there with
// __builtin_amdgcn_sched_barrier(0) so the compiler cannot sink them past
// batch0's softmax (R11 failure: VGPR=136 proved it sank them).
// __launch_bounds__(256,2) raises the VGPR cap to 256 for the ~220 live set.
// ---------------------------------------------------------------------------
#define FOR_R(OP) OP(0) OP(1) OP(2) OP(3) OP(4) OP(5) OP(6) OP(7) OP(8) OP(9) OP(10) OP(11)
#define FOR_R2(OP, X) OP(0,X) OP(1,X) OP(2,X) OP(3,X) OP(4,X) OP(5,X) OP(6,X) OP(7,X) OP(8,X) OP(9,X) OP(10,X) OP(11,X)

#define TRANS_BIAS(O, F, P, PX, PY, PZ)                                 \
    const floatx4 O##A0 = {F##0 .x, F##2 .x, F##4 .x, F##6 .x};         \
    const floatx4 O##A1 = {F##0 .y, F##2 .y, F##4 .y, F##6 .y};         \
    const floatx4 O##A2 = {F##0 .z, F##2 .z, F##4 .z, F##6 .z};         \
    const floatx4 O##A3 = {F##0 .w, F##2 .w, F##4 .w, F##6 .w};         \
    const floatx4 O##A4 = {F##1 .x, F##3 .x, F##5 .x, F##7 .x};         \
    const floatx4 O##A5 = {F##1 .y, F##3 .y, F##5 .y, F##7 .y};         \
    const floatx4 O##A6 = {F##1 .z, F##3 .z, F##5 .z, F##7 .z};         \
    const floatx4 O##A7 = {F##1 .w, F##3 .w, F##5 .w, F##7 .w};         \
    const floatx4 O##A8 = {P##0 .x, P##0 .w, P##1 .z, P##2 .y};         \
    const floatx4 O##A9 = {P##0 .y, P##1 .x, P##1 .w, P##2 .z};         \
    const floatx4 O##A10 = {P##0 .z, P##1 .y, P##2 .x, P##2 .w};        \
    const floatx4 O##B0 = {F##8 .x, F##10 .x, F##12 .x, F##14 .x};      \
    const floatx4 O##B1 = {F##8 .y, F##10 .y, F##12 .y, F##14 .y};      \
    const floatx4 O##B2 = {F##8 .z, F##10 .z, F##12 .z, F##14 .z};      \
    const floatx4 O##B3 = {F##8 .w, F##10 .w, F##12 .w, F##14 .w};      \
    const floatx4 O##B4 = {F##9 .x, F##11 .x, F##13 .x, F##15 .x};      \
    const floatx4 O##B5 = {F##9 .y, F##11 .y, F##13 .y, F##15 .y};      \
    const floatx4 O##B6 = {F##9 .z, F##11 .z, F##13 .z, F##15 .z};      \
    const floatx4 O##B7 = {F##9 .w, F##11 .w, F##13 .w, F##15 .w};      \
    const floatx4 O##B8 = {P##3 .x, P##3 .w, P##4 .z, P##5 .y};         \
    const floatx4 O##B9 = {P##3 .y, P##4 .x, P##4 .w, P##5 .z};         \
    const floatx4 O##B10 = {P##3 .z, P##4 .y, P##5 .x, P##5 .w};        \
    const floatx4 O##DXA = PX - O##A8, O##DYA = PY - O##A9, O##DZA = PZ - O##A10; \
    const floatx4 O##BIA = nfc * (O##DXA * O##DXA + O##DYA * O##DYA + O##DZA * O##DZA); \
    const floatx4 O##DXB = PX - O##B8, O##DYB = PY - O##B9, O##DZB = PZ - O##B10; \
    const floatx4 O##BIB = nfc * (O##DXB * O##DXB + O##DYB * O##DYB + O##DZB * O##DZB);

#define JLOOP(PA, PB, SQ)                                               \
    _Pragma("unroll 2")                                                 \
    for (int j = 0; j < 32; j++) {                                      \
        const floatx4 w0 = *reinterpret_cast<const floatx4*>(&sW[j * 12]); \
        const floatx4 w1 = *reinterpret_cast<const floatx4*>(&sW[j * 12 + 4]); \
        const floatx4 w2 = *reinterpret_cast<const floatx4*>(&sW[j * 12 + 8]); \
        const floatx4 q0 = *reinterpret_cast<const floatx4*>(&SQ[j * 12]); \
        const floatx4 q1 = *reinterpret_cast<const floatx4*>(&SQ[j * 12 + 4]); \
        const floatx4 q2 = *reinterpret_cast<const floatx4*>(&SQ[j * 12 + 8]); \
        floatx4 HA = {w2.w, w2.w, w2.w, w2.w};                          \
        floatx4 HB = HA;                                                \
        HA += PA##0 * w0.x;  HB += PB##0 * w0.x;                        \
        HA += PA##1 * w0.y;  HB += PB##1 * w0.y;                        \
        HA += PA##2 * w0.z;  HB += PB##2 * w0.z;                        \
        HA += PA##3 * w0.w;  HB += PB##3 * w0.w;                        \
        HA += PA##4 * w1.x;  HB += PB##4 * w1.x;                        \
        HA += PA##5 * w1.y;  HB += PB##5 * w1.y;                        \
        HA += PA##6 * w1.z;  HB += PB##6 * w1.z;                        \
        HA += PA##7 * w1.w;  HB += PB##7 * w1.w;                        \
        HA += PA##8 * w2.x;  HB += PB##8 * w2.x;                        \
        HA += PA##9 * w2.y;  HB += PB##9 * w2.y;                        \
        HA += PA##10 * w2.z; HB += PB##10 * w2.z;                       \
        HA.x = fmaxf(HA.x, 0.0f); HA.y = fmaxf(HA.y, 0.0f);             \
        HA.z = fmaxf(HA.z, 0.0f); HA.w = fmaxf(HA.w, 0.0f);             \
        HB.x = fmaxf(HB.x, 0.0f); HB.y = fmaxf(HB.y, 0.0f);             \
        HB.z = fmaxf(HB.z, 0.0f); HB.w = fmaxf(HB.w, 0.0f);             \
        AA0 += HA * q0.x;  AB0 += HB * q0.x;                            \
        AA1 += HA * q0.y;  AB1 += HB * q0.y;                            \
        AA2 += HA * q0.z;  AB2 += HB * q0.z;                            \
        AA3 += HA * q0.w;  AB3 += HB * q0.w;                            \
        AA4 += HA * q1.x;  AB4 += HB * q1.x;                            \
        AA5 += HA * q1.y;  AB5 += HB * q1.y;                            \
        AA6 += HA * q1.z;  AB6 += HB * q1.z;                            \
        AA7 += HA * q1.w;  AB7 += HB * q1.w;                            \
        AA8 += HA * q2.x;  AB8 += HB * q2.x;                            \
        AA9 += HA * q2.y;  AB9 += HB * q2.y;                            \
        AA10 += HA * q2.z; AB10 += HB * q2.z;                           \
        AA11 += HA * q2.w; AB11 += HB * q2.w;                           \
    }

#define MASK_R(r)                                            \
    AA##r .x = ((mbA.x >> r) & 1) ? AA##r .x : -FLT_MAX;     \
    AA##r .y = ((mbA.y >> r) & 1) ? AA##r .y : -FLT_MAX;     \
    AA##r .z = ((mbA.z >> r) & 1) ? AA##r .z : -FLT_MAX;     \
    AA##r .w = ((mbA.w >> r) & 1) ? AA##r .w : -FLT_MAX;     \
    AB##r .x = ((mbB.x >> r) & 1) ? AB##r .x : -FLT_MAX;     \
    AB##r .y = ((mbB.y >> r) & 1) ? AB##r .y : -FLT_MAX;     \
    AB##r .z = ((mbB.z >> r) & 1) ? AB##r .z : -FLT_MAX;     \
    AB##r .w = ((mbB.w >> r) & 1) ? AB##r .w : -FLT_MAX;

#define WMAX2_R(r, RM) {                                                \
    float v = fmaxf(fmaxf(fmaxf(AA##r .x, AA##r .y), fmaxf(AA##r .z, AA##r .w)), \
                    fmaxf(fmaxf(AB##r .x, AB##r .y), fmaxf(AB##r .z, AB##r .w))); \
    _Pragma("unroll")                                                   \
    for (int off = 32; off >= 1; off >>= 1) v = fmaxf(v, __shfl_xor(v, off)); \
    if (lane == 0) RM[wave * 12 + r] = v; }

#define FMAX2_R(r, RM) float M##r = RM[r];                              \
    { _Pragma("unroll")                                                 \
      for (int w = 1; w < 4; w++) M##r = fmaxf(M##r, RM[w * 12 + r]); }

#define EXP2_R(r, RS) {                                                 \
    AA##r .x = __expf(AA##r .x - M##r); AA##r .y = __expf(AA##r .y - M##r); \
    AA##r .z = __expf(AA##r .z - M##r); AA##r .w = __expf(AA##r .w - M##r); \
    AB##r .x = __expf(AB##r .x - M##r); AB##r .y = __expf(AB##r .y - M##r); \
    AB##r .z = __expf(AB##r .z - M##r); AB##r .w = __expf(AB##r .w - M##r); \
    float v = ((AA##r .x + AA##r .y) + (AA##r .z + AA##r .w))           \
            + ((AB##r .x + AB##r .y) + (AB##r .z + AB##r .w));          \
    _Pragma("unroll")                                                   \
    for (int off = 32; off >= 1; off >>= 1) v += __shfl_xor(v, off);    \
    if (lane == 0) RS[wave * 12 + r] = v; }

#define FSUM2_R(r, RS) float S##r = RS[r];                              \
    { _Pragma("unroll")                                                 \
      for (int w = 1; w < 4; w++) S##r += RS[w * 12 + r]; }             \
    S##r = 1.0f / S##r;

#define STORE2_R(r, OUTP) {                                             \
    floatx4 vA = AA##r * S##r;                                          \
    floatx4 vB = AB##r * S##r;                                          \
    __builtin_nontemporal_store(vA, reinterpret_cast<floatx4*>(OUTP + (size_t)r * N_)); \
    __builtin_nontemporal_store(vB, reinterpret_cast<floatx4*>(OUTP + (size_t)r * N_ + 4)); }

__global__ void __launch_bounds__(256, 2) main_kernel(
    const float* __restrict__ ledf,     // [B,N,8]
    const float* __restrict__ ledp,     // [B,N,3]
    const float* __restrict__ prevp,    // [B,3]
    const int*   __restrict__ maskbits, // [N]
    const float* __restrict__ WkT,      // [32][12]
    const float* __restrict__ qpT,      // [B][32][12]
    const float* __restrict__ cc,       // [B*R]
    const float* __restrict__ sigp,     // [1]
    float* __restrict__ out)            // [B,R,N]
{
    const int bid = blockIdx.x;          // 0..511
    const int b0 = bid, b1 = bid + 512;
    const int tid = threadIdx.x;
    const int lane = tid & 63;
    const int wave = tid >> 6;           // 0..3
    const int n0 = tid * 8;

    __shared__ float sW[384], sQ0[384], sQ1[384];
    __shared__ float redM0[48], redS0[48], redM1[48], redS1[48];

    for (int i = tid; i < 384; i += 256) {
        sW[i] = WkT[i];
        sQ0[i] = qpT[(size_t)b0 * 384 + i];
        sQ1[i] = qpT[(size_t)b1 * 384 + i];
    }

    const float sig = sigp[0];
    const float nfc = -0.5f / (sig * sig);
    const float p0a = prevp[b0 * 3 + 0], p1a = prevp[b0 * 3 + 1], p2a = prevp[b0 * 3 + 2];
    const float p0b = prevp[b1 * 3 + 0], p1b = prevp[b1 * 3 + 1], p2b = prevp[b1 * 3 + 2];
    const float* __restrict__ ccb0 = cc + b0 * 12;
    const float* __restrict__ ccb1 = cc + b1 * 12;

    // ---- batch0 raw loads
    const floatx4* pf  = reinterpret_cast<const floatx4*>(ledf + ((size_t)b0 * N_ + n0) * 8);
    const floatx4* pp4 = reinterpret_cast<const floatx4*>(ledp + ((size_t)b0 * N_ + n0) * 3);
    const int4*    pm  = reinterpret_cast<const int4*>(maskbits + n0);
    const floatx4 F0 = pf[0],  F1 = pf[1],  F2 = pf[2],  F3 = pf[3];
    const floatx4 F4 = pf[4],  F5 = pf[5],  F6 = pf[6],  F7 = pf[7];
    const floatx4 F8 = pf[8],  F9 = pf[9],  F10 = pf[10], F11 = pf[11];
    const floatx4 F12 = pf[12], F13 = pf[13], F14 = pf[14], F15 = pf[15];
    const floatx4 pa0 = pp4[0], pa1 = pp4[1], pa2 = pp4[2];
    const floatx4 pa3 = pp4[3], pa4 = pp4[4], pa5 = pp4[5];
    const int4 mbA = pm[0], mbB = pm[1];     // mask is batch-independent

    TRANS_BIAS(X, F, pa, p0a, p1a, p2a)

#define INIT_R(r) floatx4 AA##r = XBIA + ccb0[r]; floatx4 AB##r = XBIB + ccb0[r];
    FOR_R(INIT_R)

    __syncthreads();   // staging visible

    JLOOP(XA, XB, sQ0)
    FOR_R(MASK_R)

    // ---- issue batch1 loads NOW; sched_barrier(0) pins them above softmax0
    const floatx4* gf  = reinterpret_cast<const floatx4*>(ledf + ((size_t)b1 * N_ + n0) * 8);
    const floatx4* gp4 = reinterpret_cast<const floatx4*>(ledp + ((size_t)b1 * N_ + n0) * 3);
    const floatx4 G0 = gf[0],  G1 = gf[1],  G2 = gf[2],  G3 = gf[3];
    const floatx4 G4 = gf[4],  G5 = gf[5],  G6 = gf[6],  G7 = gf[7];
    const floatx4 G8 = gf[8],  G9 = gf[9],  G10 = gf[10], G11 = gf[11];
    const floatx4 G12 = gf[12], G13 = gf[13], G14 = gf[14], G15 = gf[15];
    const floatx4 ga0 = gp4[0], ga1 = gp4[1], ga2 = gp4[2];
    const floatx4 ga3 = gp4[3], ga4 = gp4[4], ga5 = gp4[5];
    __builtin_amdgcn_sched_barrier(0);   // loads must be ISSUED before this

    // ---- batch0 softmax + store (batch1 loads in flight underneath)
    {
        FOR_R2(WMAX2_R, redM0)
        __syncthreads();
        FOR_R2(FMAX2_R, redM0)
        FOR_R2(EXP2_R, redS0)
        __syncthreads();
        FOR_R2(FSUM2_R, redS0)
        float* outp = out + (size_t)b0 * R_ * N_ + n0;
        FOR_R2(STORE2_R, outp)
    }

    // ---- batch1 compute (store drain of batch0 overlaps this)
    TRANS_BIAS(Y, G, ga, p0b, p1b, p2b)

#define REINIT_R(r) AA##r = YBIA + ccb1[r]; AB##r = YBIB + ccb1[r];
    FOR_R(REINIT_R)

    JLOOP(YA, YB, sQ1)
    FOR_R(MASK_R)

    {
        FOR_R2(WMAX2_R, redM1)
        __syncthreads();
        FOR_R2(FMAX2_R, redM1)
        FOR_R2(EXP2_R, redS1)
        __syncthreads();
        FOR_R2(FSUM2_R, redS1)
        float* outp = out + (size_t)b1 * R_ * N_ + n0;
        FOR_R2(STORE2_R, outp)
    }
}

// ---------------------------------------------------------------------------
extern "C" void kernel_launch(void* const* d_in, const int* in_sizes, int n_in,
                              void* d_out, int out_size, void* d_ws, size_t ws_size,
                              hipStream_t stream) {
    const float* rss  = (const float*)d_in[0];
    const float* ledf = (const float*)d_in[1];
    const float* ledp = (const float*)d_in[2];
    const float* prevp= (const float*)d_in[3];
    const int*   mask = (const int*)  d_in[4];
    const float* Wg1  = (const float*)d_in[5];
    const float* bg1  = (const float*)d_in[6];
    const float* Wg2  = (const float*)d_in[7];
    const float* bg2  = (const float*)d_in[8];
    const float* Wq1  = (const float*)d_in[9];
    const float* bq1  = (const float*)d_in[10];
    const float* Wq2  = (const float*)d_in[11];
    const float* bq2  = (const float*)d_in[12];
    const float* Wk1  = (const float*)d_in[13];
    const float* bk1  = (const float*)d_in[14];
    const float* Wk2  = (const float*)d_in[15];
    const float* bk2  = (const float*)d_in[16];
    const float* sigp = (const float*)d_in[17];

    float* out = (float*)d_out;
    float* inten = out + (size_t)B_ * R_ * N_;     // intensity_weight [B,R] tail

    float* qpT      = (float*)d_ws;                // [B][32][12]
    float* cc       = qpT + (size_t)B_ * 384;      // [B*R]
    int*   maskbits = (int*)(cc + B_ * R_);        // [N]
    float* Mmat     = (float*)(maskbits + N_);     // [32,32]
    float* uvec     = Mmat + 1024;                 // [32]
    float* vvec     = uvec + 32;                   // [32]
    float* k0p      = vvec + 32;                   // [1]
    float* WkT      = k0p + 4;                     // [32*12] (16B aligned)

    const_kernel<<<1, 1024, 0, stream>>>(Wq2, bq2, Wk2, bk2, Wk1, bk1,
                                         Mmat, uvec, vvec, k0p, WkT);

    prep_kernel<<<(B_ * R_ + 255) / 256, 256, 0, stream>>>(
        rss, Wg1, bg1, Wg2, bg2, Wq1, bq1,
        Mmat, uvec, vvec, k0p, mask, qpT, cc, maskbits, inten);

    main_kernel<<<512, 256, 0, stream>>>(
        ledf, ledp, prevp, maskbits, WkT, qpT, cc, sigp, out);
}